// Round 22
// baseline (286.025 us; speedup 1.0000x reference)
//
#include <hip/hip_runtime.h>
#include <stdint.h>

// GraphConvLayer: out[n,:] = W[type[n]] @ (A @ x)[n,:]
// N=16384, D=128, T=8.  A is 1 GiB f32 read exactly once -> HBM floor ~163us.
// Round 22 = Round 21 (best, 285.8us) at 1024 threads (16 waves = 4/SIMD).
// Burst lever exhausted (+41/+13/+3.7 for 512B/1KB/2KB); residual ~1650cy/
// phase attributed to latency serialization at only 2 waves/SIMD. Same
// schedule/buffers: A bf16 2x16KB + X 3x32KB (128KB), 2KB A-bursts (AL8 =
// tiles t..t+3, offsets 0..1792 per row), 1 barrier/phase, counted vmcnt.
// New per-wave shapes: wave tile 16x32 (1 A-frag x 2 X-frags, 8 MFMA),
// A-staging 1 row/thread, XD = 2 calls/wave. Ledger (younger-op counting):
// steady TOP 2/2/2/10, WAITV(8) before p-store, prologue WAITV(4),
// tail TOP 2/2/2/0. AL8 only at A2 (all parities dead - R20 lesson).

#define N_NODES 16384
#define DIM     128
#define NTYPES  8
#define BM      64
#define BK      128
#define NT_K    (N_NODES / BK)   // 128 phases

typedef float  f32x4  __attribute__((ext_vector_type(4)));
typedef __bf16 bf16x4 __attribute__((ext_vector_type(4)));
typedef __bf16 bf16x8 __attribute__((ext_vector_type(8)));

__device__ __attribute__((aligned(16))) unsigned short g_xT[DIM * N_NODES];      // [d][n], 4 MiB bf16
__device__ __attribute__((aligned(16))) unsigned short g_Wb[NTYPES * DIM * DIM]; // [t][o][d], 256 KiB

__device__ __forceinline__ unsigned int f2b(float f) {
    unsigned int u = __float_as_uint(f);
    u += 0x7FFFu + ((u >> 16) & 1u);   // round-to-nearest-even
    return u >> 16;
}
#define BF_LO(u) __uint_as_float((unsigned int)(u) << 16)
#define BF_HI(u) __uint_as_float((unsigned int)(u) & 0xFFFF0000u)

__device__ __forceinline__ bf16x4 cvt4(const f32x4 v) {
    bf16x4 r;
    r[0] = (__bf16)v[0]; r[1] = (__bf16)v[1]; r[2] = (__bf16)v[2]; r[3] = (__bf16)v[3];
    return r;
}

// ---------------- fused prep kernel ----------------

__global__ void prep_all(const float* __restrict__ x, const float* __restrict__ w) {
    const int tid = threadIdx.x;
    if (blockIdx.x < 64) {
        int n = blockIdx.x * 256 + tid;
        const float* row = x + (size_t)n * DIM;
#pragma unroll
        for (int d0 = 0; d0 < DIM; d0 += 4) {
            float4 v = *(const float4*)(row + d0);
            g_xT[(d0 + 0) * N_NODES + n] = (unsigned short)f2b(v.x);
            g_xT[(d0 + 1) * N_NODES + n] = (unsigned short)f2b(v.y);
            g_xT[(d0 + 2) * N_NODES + n] = (unsigned short)f2b(v.z);
            g_xT[(d0 + 3) * N_NODES + n] = (unsigned short)f2b(v.w);
        }
    } else {
        int base = ((blockIdx.x - 64) * 256 + tid) * 16;
#pragma unroll
        for (int j = 0; j < 4; ++j) {
            float4 v = *(const float4*)(w + base + j * 4);
            ushort4 o;
            o.x = (unsigned short)f2b(v.x); o.y = (unsigned short)f2b(v.y);
            o.z = (unsigned short)f2b(v.z); o.w = (unsigned short)f2b(v.w);
            *(ushort4*)(g_Wb + base + j * 4) = o;
        }
    }
}

// ---------------- main fused kernel ----------------

#define AB_BYTES 16384   // A tile bf16: 64 rows x 256B
#define XB_BYTES 32768   // X tile bf16: 128 d-rows x 256B

#define GLOAD16(g, l) __builtin_amdgcn_global_load_lds(                         \
    (const __attribute__((address_space(1))) unsigned int*)(g),                 \
    (__attribute__((address_space(3))) unsigned int*)(l), 16, 0, 0)

#define ALOADI(reg, ptr, off) \
    asm volatile("global_load_dwordx4 %0, %1, off offset:" #off : "=v"(reg) : "v"(ptr))

// AL8: tiles t..t+3 (p/q/r/s), each 512B/row, 8 back-to-back loads per row =
// 2KB sequential per page visit. One row per thread (arow = w*4 + (l>>4)).
#define ISSUE_AL8() do {                          \
    ALOADI(pa, pA,    0); ALOADI(pb, pA,  256);   \
    ALOADI(qa, pA,  512); ALOADI(qb, pA,  768);   \
    ALOADI(ra, pA, 1024); ALOADI(rb, pA, 1280);   \
    ALOADI(sa, pA, 1536); ALOADI(sb, pA, 1792);   \
    pA += 512;                                    \
} while (0)

// XD: 2 calls per wave (halves d 0-63, 64-127), 1KB linear dest each
#define ISSUE_XD(Xb) do {                        \
    GLOAD16(gX0, (Xb) + wq);                     \
    GLOAD16(gX1, (Xb) + 16384 + wq);             \
    gX0 += BK; gX1 += BK;                        \
} while (0)

// store one parity (this thread's row chunk, two 8B halves, XOR-swizzled)
#define STOREA(As, lo, hi) do {                  \
    *(bf16x4*)((As) + awLo) = cvt4(lo);          \
    *(bf16x4*)((As) + awHi) = cvt4(hi);          \
} while (0)

// one k-substep: 1 A-frag x 2 X-frags -> 2 MFMA (A and X share `off`)
#define KS(Ab, Xb, off) do {                                                    \
    bf16x8 a_  = *(const bf16x8*)((Ab) + arA + (off));                          \
    bf16x8 b0_ = *(const bf16x8*)((Xb) + xB0 + (off));                          \
    bf16x8 b1_ = *(const bf16x8*)((Xb) + xB1 + (off));                          \
    acc00 = __builtin_amdgcn_mfma_f32_16x16x32_bf16(a_, b0_, acc00, 0, 0, 0);   \
    acc01 = __builtin_amdgcn_mfma_f32_16x16x32_bf16(a_, b1_, acc01, 0, 0, 0);   \
} while (0)

#define COMPUTE(Ab, Xb) do {      \
    KS(Ab, Xb, off0);             \
    KS(Ab, Xb, off1);             \
    KS(Ab, Xb, off2);             \
    KS(Ab, Xb, off3);             \
} while (0)

#define WAITV(N) do {                                        \
    asm volatile("s_waitcnt vmcnt(" #N ")" ::: "memory");    \
    __builtin_amdgcn_sched_barrier(0);                       \
} while (0)

#define TOP(VM) do {                                                            \
    asm volatile("s_waitcnt vmcnt(" #VM ") lgkmcnt(0)\n\ts_barrier" ::: "memory"); \
    __builtin_amdgcn_sched_barrier(0);                                          \
} while (0)

// Phase macros (t mod 4). Ledger (XD=2 ops/phase, AL8=8 at A2):
// A0: outstanding [AL8-rest 6, XD(t)2, XD(t+1)2] -> TOP(2); store q.
// A1: [XD(t)2, XD(t+1)2] -> TOP(2); store r.
// A2: TOP(2); store s; ISSUE_AL8 (parities all dead); ISSUE_XD.
// A3: [XD(t)2, AL8 8, XD(t+1)2] -> TOP(10); WAITV(8) -> store p.
#define PH_A0(Xc, Xi) do { TOP(2);  COMPUTE(Ab0, Xc); STOREA(Ab1, qa, qb); ISSUE_XD(Xi); } while (0)
#define PH_A1(Xc, Xi) do { TOP(2);  COMPUTE(Ab1, Xc); STOREA(Ab0, ra, rb); ISSUE_XD(Xi); } while (0)
#define PH_A2(Xc, Xi) do { TOP(2);  COMPUTE(Ab0, Xc); STOREA(Ab1, sa, sb); ISSUE_AL8(); ISSUE_XD(Xi); } while (0)
#define PH_A3(Xc, Xi) do { TOP(10); COMPUTE(Ab1, Xc); WAITV(8); STOREA(Ab0, pa, pb); ISSUE_XD(Xi); } while (0)

__global__ __launch_bounds__(1024, 1) void gconv_main(
    const float* __restrict__ adj,
    const int* __restrict__ types,
    float* __restrict__ out)
{
    __shared__ __align__(16) unsigned char lds[3 * XB_BYTES + 2 * AB_BYTES]; // 131072 B
    unsigned char* X0 = lds;
    unsigned char* X1 = lds + XB_BYTES;
    unsigned char* X2 = lds + 2 * XB_BYTES;
    unsigned char* Ab0 = lds + 3 * XB_BYTES;
    unsigned char* Ab1 = Ab0 + AB_BYTES;

    const int tid  = threadIdx.x;
    const int w    = tid >> 6;          // 0..15
    const int l    = tid & 63;
    const int m0   = blockIdx.x * BM;

    const int mrow = (w & 3) * 16;      // wave tile: 16 rows x 32 cols
    const int ncol = (w >> 2) * 32;
    const int h    = l >> 4;            // k-quarter within ksub

    f32x4 acc00 = {}, acc01 = {};

    // ---- A staging: one row per thread: arow = w*4 + (l>>4), chunk (l&15) ----
    const int arow = w * 4 + (l >> 4);
    const float* pA = adj + (size_t)(m0 + arow) * N_NODES + (l & 15) * 4;
    // bf16 store addrs (granule16 XOR arow&7): lo = floats [0,64), hi = [64,128)
    const int gl  = (l & 15) >> 1;
    const int sub = ((l & 15) & 1) << 3;
    const int awLo = arow * 256 + (((gl)     ^ (arow & 7)) << 4) + sub;
    const int awHi = arow * 256 + (((8 + gl) ^ (arow & 7)) << 4) + sub;

    // ---- X DMA: call j covers d = j*64 + w*4 + (l>>4), chunk (l&15) ----
    const int xd0 = w * 4 + (l >> 4);
    const unsigned short* gX0 = g_xT + (size_t)xd0 * N_NODES + (((l & 15) ^ (xd0 & 7)) << 3);
    const unsigned short* gX1 = g_xT + (size_t)(64 + xd0) * N_NODES + (((l & 15) ^ (xd0 & 7)) << 3);
    const int wq = w << 10;             // wave's 1KB slot within each 16KB half

    // ---- compute-side bases/offsets (XOR matches write swizzle; row&7 = l&7) ----
    const int arA = (mrow + (l & 15)) * 256;
    const int xB0 = (ncol +  0 + (l & 15)) * 256;
    const int xB1 = (ncol + 16 + (l & 15)) * 256;
    const int off0 = (( 0 + h) ^ (l & 7)) << 4;
    const int off1 = (( 4 + h) ^ (l & 7)) << 4;
    const int off2 = (( 8 + h) ^ (l & 7)) << 4;
    const int off3 = ((12 + h) ^ (l & 7)) << 4;

    // ---- A register parities: tiles 4j..4j+3 -> p/q/r/s (lo,hi each) ----
    f32x4 pa, pb, qa, qb, ra, rb, sa, sb;

    // ---- prologue: AL8(tiles 0-3) [8], XD(0) [2], XD(1) [2]; store A(0) ----
    ISSUE_AL8();
    ISSUE_XD(X0);
    ISSUE_XD(X1);
    WAITV(4);                     // AL8 done (XD0+XD1 = 4 younger)
    STOREA(Ab0, pa, pb);

    // ---- t = 0..119: 10 x period-12 (A period 4, X period 3) ----
    for (int i = 0; i < 10; ++i) {
        PH_A0(X0, X2); PH_A1(X1, X0); PH_A2(X2, X1); PH_A3(X0, X2);
        PH_A0(X1, X0); PH_A1(X2, X1); PH_A2(X0, X2); PH_A3(X1, X0);
        PH_A0(X2, X1); PH_A1(X0, X2); PH_A2(X1, X0); PH_A3(X2, X1);
    }
    // ---- t = 120..123 (AL8@122 loads tiles 124-127; p(124) stored @123) ----
    PH_A0(X0, X2); PH_A1(X1, X0); PH_A2(X2, X1); PH_A3(X0, X2);
    // ---- tail t = 124..127 (no more AL8) ----
    TOP(2);                       // t=124: [AL8-rest 6, XD(124)2, XD(125)2] -> leave XD(125)
    COMPUTE(Ab0, X1);
    STOREA(Ab1, qa, qb);          // A(125)
    ISSUE_XD(X0);                 // XD(126)
    TOP(2);                       // t=125: [XD(125)2, XD(126)2]
    COMPUTE(Ab1, X2);
    STOREA(Ab0, ra, rb);          // A(126)
    ISSUE_XD(X1);                 // XD(127)
    TOP(2);                       // t=126: [XD(126)2, XD(127)2]
    COMPUTE(Ab0, X0);
    STOREA(Ab1, sa, sb);          // A(127)
    TOP(0);                       // t=127: full drain
    COMPUTE(Ab1, X1);
    __syncthreads();              // before reusing LDS as agg

    // ---- epilogue: acc -> LDS agg (f32), then per-row W[type] dots ----
    float* agg = (float*)lds;   // [64][132] = 33792 B
#pragma unroll
    for (int rr = 0; rr < 4; ++rr) {
        const int e0 = (mrow + h * 4 + rr) * 132 + ncol + (l & 15);
        agg[e0 +  0] = acc00[rr];
        agg[e0 + 16] = acc01[rr];
    }
    __syncthreads();

    const int rbase = w * 4;   // 4 rows per wave (16 waves)
    for (int rr = 0; rr < 4; ++rr) {
        const int rw = rbase + rr;
        const int nn = m0 + rw;
        const int ty = types[nn];                      // wave-uniform
        const unsigned short* Wt = g_Wb + ty * (DIM * DIM);
        const int o0 = l * 2;
        const float* aggRow = agg + rw * 132;
        float t0 = 0.f, t1 = 0.f;
#pragma unroll
        for (int d0 = 0; d0 < DIM; d0 += 8) {
            float4 ga = *(const float4*)(aggRow + d0);
            float4 gb = *(const float4*)(aggRow + d0 + 4);
            uint4 wa = *(const uint4*)(Wt + o0 * DIM + d0);
            uint4 wb = *(const uint4*)(Wt + (o0 + 1) * DIM + d0);
            t0 += ga.x * BF_LO(wa.x) + ga.y * BF_HI(wa.x) + ga.z * BF_LO(wa.y) + ga.w * BF_HI(wa.y);
            t0 += gb.x * BF_LO(wa.z) + gb.y * BF_HI(wa.z) + gb.z * BF_LO(wa.w) + gb.w * BF_HI(wa.w);
            t1 += ga.x * BF_LO(wb.x) + ga.y * BF_HI(wb.x) + ga.z * BF_LO(wb.y) + ga.w * BF_HI(wb.y);
            t1 += gb.x * BF_LO(wb.z) + gb.y * BF_HI(wb.z) + gb.z * BF_LO(wb.w) + gb.w * BF_HI(wb.w);
        }
        float2 res; res.x = t0; res.y = t1;
        *(float2*)(out + (size_t)nn * DIM + o0) = res;
    }
}

// ---------------- launch ----------------

extern "C" void kernel_launch(void* const* d_in, const int* in_sizes, int n_in,
                              void* d_out, int out_size, void* d_ws, size_t ws_size,
                              hipStream_t stream) {
    const float* x     = (const float*)d_in[0];
    const int*   types = (const int*)d_in[1];
    const float* adj   = (const float*)d_in[2];
    const float* wt    = (const float*)d_in[3];
    float* out = (float*)d_out;

    hipLaunchKernelGGL(prep_all, dim3(96), dim3(256), 0, stream, x, wt);
    hipLaunchKernelGGL(gconv_main, dim3(N_NODES / BM), dim3(1024), 0, stream, adj, types, out);
}